// Round 5
// baseline (771.443 us; speedup 1.0000x reference)
//
#include <hip/hip_runtime.h>
#include <stdint.h>

typedef unsigned short u16;
typedef unsigned int   u32;

typedef __attribute__((ext_vector_type(8))) short bf16x8;
typedef __attribute__((ext_vector_type(4))) float f32x4;
typedef __attribute__((ext_vector_type(4))) u32   u32x4;

#define NNODES 8000
#define BSZ    32
#define UNITS  64
#define EDG    64000
#define EDGPAD 120000        /* worst case: 64000 + 7*8000 */
#define ROWCH  288           /* 16B chunks per node row: 9 s-slices * 32 b */
#define ROWU16 2304
#define KLIN   480           /* 5 matrices * 96 padded k */
#define HXROW  512000
#define INROW  16000
#define NROW   18432000      /* NNODES*ROWU16 */
#define NSTEPS 15

__device__ __forceinline__ u32 f2bf(float f){
    u32 u = __float_as_uint(f);
    return (u + 0x7FFFu + ((u >> 16) & 1u)) >> 16;   // RNE
}
__device__ __forceinline__ float bfu(u16 s){ return __uint_as_float(((u32)s) << 16); }
__device__ __forceinline__ float lo16(u32 u){ return __uint_as_float(u << 16); }
__device__ __forceinline__ float hi16(u32 u){ return __uint_as_float(u & 0xFFFF0000u); }
__device__ __forceinline__ float sigm(float x){ return 1.f / (1.f + __expf(-x)); }

// non-temporal helpers: keep streams out of L2 so the gather slice stays resident
__device__ __forceinline__ uint4 ntld4(const uint4* p){
    u32x4 v = __builtin_nontemporal_load((const u32x4*)p);
    uint4 r; r.x = v.x; r.y = v.y; r.z = v.z; r.w = v.w; return r;
}
__device__ __forceinline__ void ntst4(uint4* p, uint4 o){
    u32x4 v; v.x = o.x; v.y = o.y; v.z = o.z; v.w = o.w;
    __builtin_nontemporal_store(v, (u32x4*)p);
}

#define GLDS(gsrc, ldst) \
    __builtin_amdgcn_global_load_lds((const __attribute__((address_space(1))) void*)(gsrc), \
                                     (__attribute__((address_space(3))) void*)(ldst), 16, 0, 0)

// ---------------- CSR build for support 0 (degrees padded to multiple of 8) ----------------
__global__ void hist_k(const int* __restrict__ rows, int* __restrict__ counts){
    int e = blockIdx.x * 256 + threadIdx.x;
    if (e < EDG) atomicAdd(&counts[rows[e]], 1);
}

__global__ __launch_bounds__(256) void scan_k(const int* __restrict__ counts,
                                              int* __restrict__ row_ptr,
                                              int* __restrict__ cursor){
    __shared__ int part[256];
    int t = threadIdx.x;
    int s = 0;
    for (int i = 0; i < 32; ++i){ int r = t*32 + i; if (r < NNODES) s += (counts[r] + 7) & ~7; }
    part[t] = s;
    __syncthreads();
    if (t == 0){
        int run = 0;
        for (int i = 0; i < 256; ++i){ int v = part[i]; part[i] = run; run += v; }
    }
    __syncthreads();
    int run = part[t];
    for (int i = 0; i < 32; ++i){
        int r = t*32 + i;
        if (r < NNODES){ row_ptr[r] = run; cursor[r] = run; run += (counts[r] + 7) & ~7; }
    }
    if (t == 255) row_ptr[NNODES] = run;
}

__global__ void scatter_k(const int* __restrict__ rows, const int* __restrict__ cols,
                          const float* __restrict__ vals, int* __restrict__ cursor,
                          int* __restrict__ cs, float* __restrict__ vs){
    int e = blockIdx.x * 256 + threadIdx.x;
    if (e < EDG){
        int r = rows[e];
        int slot = atomicAdd(&cursor[r], 1);
        cs[slot] = cols[e];
        vs[slot] = vals[e];
    }
}

// ---------------- W pre-permute into per-step staged layout ----------------
__global__ void prep_w_k(const float* __restrict__ W_ru, const float* __restrict__ W_c,
                         u16* __restrict__ Wt_ru, u16* __restrict__ Wt_c){
    int id = blockIdx.x * 256 + threadIdx.x;
    if (id < 128*KLIN){
        int j = id & 7;
        int cell = id >> 3;
        int col = cell & 127;
        int sq = cell >> 7;                  // st*4+q
        int kl = sq*8 + j;                   // st*32 + q*8 + j
        int m = kl / 96, fp = kl - m*96;
        u16 v = 0;
        if (fp < 66) v = (u16)f2bf(W_ru[(fp*5 + m)*128 + col]);
        Wt_ru[id] = v;
    }
    int id2 = id - 128*KLIN;
    if (id2 >= 0 && id2 < 64*KLIN){
        int j = id2 & 7;
        int cell = id2 >> 3;
        int col = cell & 63;
        int sq = cell >> 6;
        int kl = sq*8 + j;
        int m = kl / 96, fp = kl - m*96;
        u16 v = 0;
        if (fp < 66) v = (u16)f2bf(W_c[(fp*5 + m)*64 + col]);
        Wt_c[id2] = v;
    }
}

// ---------------- build x0, fp-major chunks: chunk(s,b) at s*32+b holds fp s*8..s*8+7 ----------------
__global__ __launch_bounds__(256) void build_x0_k(const float* __restrict__ inputs,
                                                  const float* __restrict__ hx,
                                                  u16* __restrict__ X0){
    __shared__ float sl[32*72];
    int n = blockIdx.x, t = threadIdx.x;
    #pragma unroll
    for (int i = 0; i < 8; ++i){
        int idx = t + i*256;                // 2048 hx elems
        int b = idx >> 6, f = idx & 63;
        sl[b*72 + 2 + f] = hx[b*HXROW + n*64 + f];
    }
    if (t < 64){
        int b = t >> 1, d = t & 1;
        sl[b*72 + d] = inputs[b*INROW + n*2 + d];
    }
    if (t < 192){
        int b = t / 6, k = t - b*6;
        sl[b*72 + 66 + k] = 0.f;
    }
    __syncthreads();
    #pragma unroll
    for (int i = 0; i < 2; ++i){
        int j = t + i*256;
        if (j < ROWCH){
            int b = j & 31, s = j >> 5;
            const float* p = &sl[b*72 + s*8];
            uint4 o;
            o.x = f2bf(p[0]) | (f2bf(p[1]) << 16);
            o.y = f2bf(p[2]) | (f2bf(p[3]) << 16);
            o.z = f2bf(p[4]) | (f2bf(p[5]) << 16);
            o.w = f2bf(p[6]) | (f2bf(p[7]) << 16);
            ((uint4*)X0)[n*ROWCH + j] = o;
        }
    }
}

__device__ __forceinline__ void acc8(float* a, uint4 q, float v){
    a[0] += v*lo16(q.x); a[1] += v*hi16(q.x);
    a[2] += v*lo16(q.y); a[3] += v*hi16(q.y);
    a[4] += v*lo16(q.z); a[5] += v*hi16(q.z);
    a[6] += v*lo16(q.w); a[7] += v*hi16(q.w);
}
__device__ __forceinline__ uint4 pack8(const float* a){
    uint4 o;
    o.x = f2bf(a[0]) | (f2bf(a[1]) << 16);
    o.y = f2bf(a[2]) | (f2bf(a[3]) << 16);
    o.z = f2bf(a[4]) | (f2bf(a[5]) << 16);
    o.w = f2bf(a[6]) | (f2bf(a[7]) << 16);
    return o;
}

// ---------------- diffusion level 1: X1a = S0*X0, X1b = S1*X0 ----------------
// XCD-sliced: block (ng, sl) = 288 thr = 8 nodes x 36 chunks of slice sl.
// Gathered array = X0 only (4.6MB/XCD). All other traffic non-temporal.
__global__ __launch_bounds__(288) void diff1_k(const u16* __restrict__ X0,
                                               u16* __restrict__ X1a, u16* __restrict__ X1b,
                                               const int* __restrict__ rp,
                                               const int* __restrict__ c0, const float* __restrict__ v0,
                                               const int* __restrict__ c1, const float* __restrict__ v1){
    const int sl = blockIdx.x & 7, ng = blockIdx.x >> 3;
    const int ln = threadIdx.x / 36, j = threadIdx.x - ln*36;
    const int n = ng*8 + ln;
    const int t = sl*36 + j;
    const uint4* xb = (const uint4*)X0;

    float a[8] = {0,0,0,0,0,0,0,0};
    float d[8] = {0,0,0,0,0,0,0,0};
    // support 1: exactly 8 edges
    {
        uint4 q[8]; float vv[8];
        #pragma unroll
        for (int i = 0; i < 8; ++i){
            int c = __builtin_nontemporal_load(&c1[n*8 + i]);
            vv[i] = __builtin_nontemporal_load(&v1[n*8 + i]);
            q[i] = xb[(size_t)c*ROWCH + t];
        }
        #pragma unroll
        for (int i = 0; i < 8; ++i) acc8(d, q[i], vv[i]);
    }
    // support 0: padded CSR (multiple of 8; filler col=0/val=0 is L2-hot)
    int e = rp[n], end = rp[n+1];
    for (; e < end; e += 8){
        uint4 q[8]; float vv[8];
        #pragma unroll
        for (int i = 0; i < 8; ++i){
            int c = __builtin_nontemporal_load(&c0[e+i]);
            vv[i] = __builtin_nontemporal_load(&v0[e+i]);
            q[i] = xb[(size_t)c*ROWCH + t];
        }
        #pragma unroll
        for (int i = 0; i < 8; ++i) acc8(a, q[i], vv[i]);
    }
    ntst4(&((uint4*)X1a)[(size_t)n*ROWCH + t], pack8(a));
    ntst4(&((uint4*)X1b)[(size_t)n*ROWCH + t], pack8(d));
}

// ---------------- diffusion level 2, support 0: X2a = 2*S0*X1a - X0 ----------------
// Gathers ONLY X1a (4.6MB/XCD sliced). pv read + result store non-temporal.
__global__ __launch_bounds__(288) void diff2s0_k(const u16* __restrict__ X0,
                                                 const u16* __restrict__ X1a,
                                                 u16* __restrict__ X2a,
                                                 const int* __restrict__ rp,
                                                 const int* __restrict__ c0, const float* __restrict__ v0){
    const int sl = blockIdx.x & 7, ng = blockIdx.x >> 3;
    const int ln = threadIdx.x / 36, j = threadIdx.x - ln*36;
    const int n = ng*8 + ln;
    const int t = sl*36 + j;
    const uint4* xa = (const uint4*)X1a;

    uint4 pv = ntld4(&((const uint4*)X0)[(size_t)n*ROWCH + t]);
    float a[8] = {0,0,0,0,0,0,0,0};
    int e = rp[n], end = rp[n+1];
    for (; e < end; e += 8){
        uint4 q[8]; float vv[8];
        #pragma unroll
        for (int i = 0; i < 8; ++i){
            int c = __builtin_nontemporal_load(&c0[e+i]);
            vv[i] = __builtin_nontemporal_load(&v0[e+i]);
            q[i] = xa[(size_t)c*ROWCH + t];
        }
        #pragma unroll
        for (int i = 0; i < 8; ++i) acc8(a, q[i], vv[i]);
    }
    float p[8] = { lo16(pv.x), hi16(pv.x), lo16(pv.y), hi16(pv.y),
                   lo16(pv.z), hi16(pv.z), lo16(pv.w), hi16(pv.w) };
    #pragma unroll
    for (int i = 0; i < 8; ++i) a[i] = 2.f*a[i] - p[i];
    ntst4(&((uint4*)X2a)[(size_t)n*ROWCH + t], pack8(a));
}

// ---------------- diffusion level 2, support 1: X2b = 2*S1*X1b - X0 ----------------
__global__ __launch_bounds__(288) void diff2s1_k(const u16* __restrict__ X0,
                                                 const u16* __restrict__ X1b,
                                                 u16* __restrict__ X2b,
                                                 const int* __restrict__ c1, const float* __restrict__ v1){
    const int sl = blockIdx.x & 7, ng = blockIdx.x >> 3;
    const int ln = threadIdx.x / 36, j = threadIdx.x - ln*36;
    const int n = ng*8 + ln;
    const int t = sl*36 + j;
    const uint4* xbb = (const uint4*)X1b;

    uint4 pv = ntld4(&((const uint4*)X0)[(size_t)n*ROWCH + t]);
    float d[8] = {0,0,0,0,0,0,0,0};
    {
        uint4 q[8]; float vv[8];
        #pragma unroll
        for (int i = 0; i < 8; ++i){
            int c = __builtin_nontemporal_load(&c1[n*8 + i]);
            vv[i] = __builtin_nontemporal_load(&v1[n*8 + i]);
            q[i] = xbb[(size_t)c*ROWCH + t];
        }
        #pragma unroll
        for (int i = 0; i < 8; ++i) acc8(d, q[i], vv[i]);
    }
    float p[8] = { lo16(pv.x), hi16(pv.x), lo16(pv.y), hi16(pv.y),
                   lo16(pv.z), hi16(pv.z), lo16(pv.w), hi16(pv.w) };
    #pragma unroll
    for (int i = 0; i < 8; ++i) d[i] = 2.f*d[i] - p[i];
    ntst4(&((uint4*)X2b)[(size_t)n*ROWCH + t], pack8(d));
}

// ---------------- GEMM1: sigmoid(Xc@W_ru + b_ru); U out; X0.state <- r*hx (bf16 RMW) ----------------
__global__ __launch_bounds__(256) void gemm_ru_k(
        const u16* X0, const u16* __restrict__ X1a, const u16* __restrict__ X2a,
        const u16* __restrict__ X1b, const u16* __restrict__ X2b,
        const u16* __restrict__ WtS,       // [(st*4+q)*128+col][8]
        const float* __restrict__ b_ru,
        u16* __restrict__ U, u16* X0st){
    __shared__ u16 Bs[2][4096];            // 2 x 8KB
    const int t = threadIdx.x;
    const int lane = t & 63, w = t >> 6;
    const int node = blockIdx.x*4 + w;
    const int cIn = lane & 15, q = lane >> 4;
    const size_t noff = (size_t)node * ROWU16;

    const u16* xp[5] = { X0 + noff, X1a + noff, X2a + noff, X1b + noff, X2b + noff };

    f32x4 acc[2][8];
    const f32x4 z4 = {0.f,0.f,0.f,0.f};
    #pragma unroll
    for (int rt = 0; rt < 2; ++rt)
        #pragma unroll
        for (int ct = 0; ct < 8; ++ct) acc[rt][ct] = z4;

    // prologue: stage B tile 0, load A tile 0
    {
        const u16* src = WtS + t*8;
        GLDS(src,        &Bs[0][w*512]);
        GLDS(src + 2048, &Bs[0][2048 + w*512]);
    }
    bf16x8 A0 = *(const bf16x8*)&xp[0][(size_t)(q*32 + cIn)*8];
    bf16x8 A1 = *(const bf16x8*)&xp[0][(size_t)(q*32 + 16 + cIn)*8];
    __syncthreads();

    int cur = 0;
    #pragma unroll
    for (int st = 0; st < NSTEPS; ++st){
        bf16x8 p0, p1;
        if (st + 1 < NSTEPS){
            const u16* src = WtS + (size_t)(st+1)*4096 + t*8;
            GLDS(src,        &Bs[cur^1][w*512]);
            GLDS(src + 2048, &Bs[cur^1][2048 + w*512]);
            const int m2 = (st+1)/3, s2 = (st+1) - m2*3;
            p0 = *(const bf16x8*)&xp[m2][(size_t)((s2*4 + q)*32 + cIn)*8];
            p1 = *(const bf16x8*)&xp[m2][(size_t)((s2*4 + q)*32 + 16 + cIn)*8];
        }
        bf16x8 cb[8];
        #pragma unroll
        for (int ct = 0; ct < 8; ++ct)
            cb[ct] = *(const bf16x8*)&Bs[cur][(q*128 + ct*16 + cIn)*8];
        #pragma unroll
        for (int ct = 0; ct < 8; ++ct){
            acc[0][ct] = __builtin_amdgcn_mfma_f32_16x16x32_bf16(A0, cb[ct], acc[0][ct], 0,0,0);
            acc[1][ct] = __builtin_amdgcn_mfma_f32_16x16x32_bf16(A1, cb[ct], acc[1][ct], 0,0,0);
        }
        __syncthreads();                    // drains vmcnt for staged tile + A prefetch
        if (st + 1 < NSTEPS){ A0 = p0; A1 = p1; }
        cur ^= 1;
    }

    // epilogue: D row=b (q*4+i within 16-tile, +16*rt), col = ct*16+cIn
    #pragma unroll
    for (int ct = 0; ct < 8; ++ct){
        int col = ct*16 + cIn;
        float bias = b_ru[col];
        #pragma unroll
        for (int rt = 0; rt < 2; ++rt){
            int b0 = rt*16 + q*4;
            f32x4 d = acc[rt][ct];
            if (ct < 4){
                int fp = 2 + col;
                int s = fp >> 3, off = fp & 7;
                #pragma unroll
                for (int i = 0; i < 4; ++i){
                    size_t idx = noff + (size_t)(s*32 + b0 + i)*8 + off;
                    float h = bfu(X0st[idx]);
                    float rg = sigm(d[i] + bias);
                    X0st[idx] = (u16)f2bf(rg * h);
                }
            } else {
                uint2 pk;
                float v0 = sigm(d[0] + bias), v1 = sigm(d[1] + bias);
                float v2 = sigm(d[2] + bias), v3 = sigm(d[3] + bias);
                pk.x = f2bf(v0) | (f2bf(v1) << 16);
                pk.y = f2bf(v2) | (f2bf(v3) << 16);
                *(uint2*)&U[(size_t)node*2048 + (col - 64)*32 + b0] = pk;
            }
        }
    }
}

// ---------------- GEMM2: c = tanh(Xc@W_c + b_c); out = u*hx + (1-u)*c ----------------
__global__ __launch_bounds__(256) void gemm_c_k(
        const u16* __restrict__ X0, const u16* __restrict__ X1a, const u16* __restrict__ X2a,
        const u16* __restrict__ X1b, const u16* __restrict__ X2b,
        const u16* __restrict__ WtS,       // [(st*4+q)*64+col][8]
        const float* __restrict__ b_c, const float* __restrict__ hx,
        const u16* __restrict__ U, float* __restrict__ out){
    __shared__ u16 Bs[2][2048];            // 2 x 4KB
    const int t = threadIdx.x;
    const int lane = t & 63, w = t >> 6;
    const int node = blockIdx.x*4 + w;
    const int cIn = lane & 15, q = lane >> 4;
    const size_t noff = (size_t)node * ROWU16;

    const u16* xp[5] = { X0 + noff, X1a + noff, X2a + noff, X1b + noff, X2b + noff };

    f32x4 acc[2][4];
    const f32x4 z4 = {0.f,0.f,0.f,0.f};
    #pragma unroll
    for (int rt = 0; rt < 2; ++rt)
        #pragma unroll
        for (int ct = 0; ct < 4; ++ct) acc[rt][ct] = z4;

    {
        const u16* src = WtS + t*8;
        GLDS(src, &Bs[0][w*512]);
    }
    bf16x8 A0 = *(const bf16x8*)&xp[0][(size_t)(q*32 + cIn)*8];
    bf16x8 A1 = *(const bf16x8*)&xp[0][(size_t)(q*32 + 16 + cIn)*8];
    __syncthreads();

    int cur = 0;
    #pragma unroll
    for (int st = 0; st < NSTEPS; ++st){
        bf16x8 p0, p1;
        if (st + 1 < NSTEPS){
            const u16* src = WtS + (size_t)(st+1)*2048 + t*8;
            GLDS(src, &Bs[cur^1][w*512]);
            const int m2 = (st+1)/3, s2 = (st+1) - m2*3;
            p0 = *(const bf16x8*)&xp[m2][(size_t)((s2*4 + q)*32 + cIn)*8];
            p1 = *(const bf16x8*)&xp[m2][(size_t)((s2*4 + q)*32 + 16 + cIn)*8];
        }
        bf16x8 cb[4];
        #pragma unroll
        for (int ct = 0; ct < 4; ++ct)
            cb[ct] = *(const bf16x8*)&Bs[cur][(q*64 + ct*16 + cIn)*8];
        #pragma unroll
        for (int ct = 0; ct < 4; ++ct){
            acc[0][ct] = __builtin_amdgcn_mfma_f32_16x16x32_bf16(A0, cb[ct], acc[0][ct], 0,0,0);
            acc[1][ct] = __builtin_amdgcn_mfma_f32_16x16x32_bf16(A1, cb[ct], acc[1][ct], 0,0,0);
        }
        __syncthreads();
        if (st + 1 < NSTEPS){ A0 = p0; A1 = p1; }
        cur ^= 1;
    }

    #pragma unroll
    for (int ct = 0; ct < 4; ++ct){
        int col = ct*16 + cIn;
        float bias = b_c[col];
        #pragma unroll
        for (int rt = 0; rt < 2; ++rt){
            int b0 = rt*16 + q*4;
            f32x4 d = acc[rt][ct];
            uint2 up = *(const uint2*)&U[(size_t)node*2048 + col*32 + b0];
            float uu[4] = { lo16(up.x), hi16(up.x), lo16(up.y), hi16(up.y) };
            #pragma unroll
            for (int i = 0; i < 4; ++i){
                float c = tanhf(d[i] + bias);
                size_t gi = (size_t)(b0 + i)*HXROW + node*64 + col;
                float h = hx[gi];
                out[gi] = uu[i]*h + (1.f - uu[i])*c;
            }
        }
    }
}

// ---------------- launch ----------------
extern "C" void kernel_launch(void* const* d_in, const int* in_sizes, int n_in,
                              void* d_out, int out_size, void* d_ws, size_t ws_size,
                              hipStream_t stream){
    const float* inputs = (const float*)d_in[0];
    const float* hx     = (const float*)d_in[1];
    const float* W_ru   = (const float*)d_in[2];
    const float* b_ru   = (const float*)d_in[3];
    const float* W_c    = (const float*)d_in[4];
    const float* b_c    = (const float*)d_in[5];
    const int*   s0r    = (const int*)d_in[6];
    const int*   s0c    = (const int*)d_in[7];
    const float* s0v    = (const float*)d_in[8];
    const int*   s1c    = (const int*)d_in[10];
    const float* s1v    = (const float*)d_in[11];
    float* out = (float*)d_out;

    char* ws = (char*)d_ws;
    size_t off = 0;
    auto alloc = [&](size_t bytes) -> char* {
        char* p = ws + off;
        off += (bytes + 255) & ~(size_t)255;
        return p;
    };
    const size_t XBYTES = (size_t)NROW*2 + 2048;   // +guard for k-tail overread of last node
    u16* X0   = (u16*)alloc(XBYTES);
    u16* X1a  = (u16*)alloc(XBYTES);
    u16* X2a  = (u16*)alloc(XBYTES);
    u16* X1b  = (u16*)alloc(XBYTES);
    u16* X2b  = (u16*)alloc(XBYTES);
    u16* U    = (u16*)alloc((size_t)NNODES*2048*2);
    u16* WtRU = (u16*)alloc((size_t)128*KLIN*2);   // 15 steps * 4096 u16
    u16* WtC  = (u16*)alloc((size_t)64*KLIN*2);    // 15 steps * 2048 u16
    int* counts  = (int*)alloc((size_t)NNODES*4);
    int* row_ptr = (int*)alloc((size_t)(NNODES+1)*4);
    int* cursor  = (int*)alloc((size_t)NNODES*4);
    int*   cols_s = (int*)alloc((size_t)EDGPAD*4);
    float* vals_s = (float*)alloc((size_t)EDGPAD*4);
    (void)ws_size; (void)in_sizes; (void)n_in; (void)out_size;

    // CSR build for support 0 (padded degrees; filler edges are col=0/val=0 via memset)
    hipMemsetAsync(counts, 0, (size_t)NNODES*4, stream);
    hipMemsetAsync(cols_s, 0, (size_t)EDGPAD*4, stream);
    hipMemsetAsync(vals_s, 0, (size_t)EDGPAD*4, stream);
    hist_k<<<250, 256, 0, stream>>>(s0r, counts);
    scan_k<<<1, 256, 0, stream>>>(counts, row_ptr, cursor);
    scatter_k<<<250, 256, 0, stream>>>(s0r, s0c, s0v, cursor, cols_s, vals_s);

    prep_w_k<<<360, 256, 0, stream>>>(W_ru, W_c, WtRU, WtC);
    build_x0_k<<<NNODES, 256, 0, stream>>>(inputs, hx, X0);

    // gconv 1 diffusion (XCD-sliced; single gathered array per kernel)
    diff1_k<<<NNODES, 288, 0, stream>>>(X0, X1a, X1b, row_ptr, cols_s, vals_s, s1c, s1v);
    diff2s0_k<<<NNODES, 288, 0, stream>>>(X0, X1a, X2a, row_ptr, cols_s, vals_s);
    diff2s1_k<<<NNODES, 288, 0, stream>>>(X0, X1b, X2b, s1c, s1v);

    // GEMM1 + sigmoid; writes U and X0.state = r*hx
    gemm_ru_k<<<NNODES/4, 256, 0, stream>>>(X0, X1a, X2a, X1b, X2b, WtRU, b_ru, U, X0);

    // gconv 2 diffusion (X0 now holds [inputs, r*hx])
    diff1_k<<<NNODES, 288, 0, stream>>>(X0, X1a, X1b, row_ptr, cols_s, vals_s, s1c, s1v);
    diff2s0_k<<<NNODES, 288, 0, stream>>>(X0, X1a, X2a, row_ptr, cols_s, vals_s);
    diff2s1_k<<<NNODES, 288, 0, stream>>>(X0, X1b, X2b, s1c, s1v);

    // GEMM2 + tanh + final gate
    gemm_c_k<<<NNODES/4, 256, 0, stream>>>(X0, X1a, X2a, X1b, X2b, WtC, b_c, hx, U, out);
}

// Round 6
// 665.449 us; speedup vs baseline: 1.1593x; 1.1593x over previous
//
#include <hip/hip_runtime.h>
#include <stdint.h>

typedef unsigned short u16;
typedef unsigned int   u32;

typedef __attribute__((ext_vector_type(8))) short bf16x8;
typedef __attribute__((ext_vector_type(4))) float f32x4;

#define NNODES 8000
#define BSZ    32
#define UNITS  64
#define EDG    64000
#define ROWCH  288           /* 16B chunks per node row: 9 s-slices * 32 b */
#define ROWU16 2304
#define KLIN   480           /* 5 matrices * 96 padded k */
#define HXROW  512000
#define INROW  16000
#define NROW   18432000      /* NNODES*ROWU16 */
#define NSTEPS 15

__device__ __forceinline__ u32 f2bf(float f){
    u32 u = __float_as_uint(f);
    return (u + 0x7FFFu + ((u >> 16) & 1u)) >> 16;   // RNE
}
__device__ __forceinline__ float bfu(u16 s){ return __uint_as_float(((u32)s) << 16); }
__device__ __forceinline__ float lo16(u32 u){ return __uint_as_float(u << 16); }
__device__ __forceinline__ float hi16(u32 u){ return __uint_as_float(u & 0xFFFF0000u); }
__device__ __forceinline__ float sigm(float x){ return 1.f / (1.f + __expf(-x)); }

#define GLDS(gsrc, ldst) \
    __builtin_amdgcn_global_load_lds((const __attribute__((address_space(1))) void*)(gsrc), \
                                     (__attribute__((address_space(3))) void*)(ldst), 16, 0, 0)

// ---------------- CSR build for support 0 ----------------
__global__ void hist_k(const int* __restrict__ rows, int* __restrict__ counts){
    int e = blockIdx.x * 256 + threadIdx.x;
    if (e < EDG) atomicAdd(&counts[rows[e]], 1);
}

__global__ __launch_bounds__(256) void scan_k(const int* __restrict__ counts,
                                              int* __restrict__ row_ptr,
                                              int* __restrict__ cursor){
    __shared__ int part[256];
    int t = threadIdx.x;
    int s = 0;
    for (int i = 0; i < 32; ++i){ int r = t*32 + i; if (r < NNODES) s += counts[r]; }
    part[t] = s;
    __syncthreads();
    if (t == 0){
        int run = 0;
        for (int i = 0; i < 256; ++i){ int v = part[i]; part[i] = run; run += v; }
    }
    __syncthreads();
    int run = part[t];
    for (int i = 0; i < 32; ++i){
        int r = t*32 + i;
        if (r < NNODES){ row_ptr[r] = run; cursor[r] = run; run += counts[r]; }
    }
    if (t == 255) row_ptr[NNODES] = run;
}

__global__ void scatter_k(const int* __restrict__ rows, const int* __restrict__ cols,
                          const float* __restrict__ vals, int* __restrict__ cursor,
                          int* __restrict__ cs, float* __restrict__ vs){
    int e = blockIdx.x * 256 + threadIdx.x;
    if (e < EDG){
        int r = rows[e];
        int slot = atomicAdd(&cursor[r], 1);
        cs[slot] = cols[e];
        vs[slot] = vals[e];
    }
}

// ---------------- W pre-permute into per-step staged layout, with Chebyshev fold ----------------
// xs = [x0, S0x1, 2*S0x2-x0, S1x1, 2*S1x2-x0]; we store y2=S*x1 raw, so fold:
//   W0' = W0 - W2 - W4 ; W2' = 2*W2 ; W4' = 2*W4  (W1, W3 unchanged)
// WtS[((st*4 + q)*C + col)*8 + j] for kl = st*32 + q*8 + j, m = kl/96, fp = kl%96 (<66 real).
__global__ void prep_w_k(const float* __restrict__ W_ru, const float* __restrict__ W_c,
                         u16* __restrict__ Wt_ru, u16* __restrict__ Wt_c){
    int id = blockIdx.x * 256 + threadIdx.x;
    if (id < 128*KLIN){
        int j = id & 7;
        int cell = id >> 3;
        int col = cell & 127;
        int sq = cell >> 7;                  // st*4+q
        int kl = sq*8 + j;                   // st*32 + q*8 + j
        int m = kl / 96, fp = kl - m*96;
        u16 v = 0;
        if (fp < 66){
            float w;
            if (m == 0)      w = W_ru[(fp*5 + 0)*128 + col] - W_ru[(fp*5 + 2)*128 + col] - W_ru[(fp*5 + 4)*128 + col];
            else if (m == 2) w = 2.f * W_ru[(fp*5 + 2)*128 + col];
            else if (m == 4) w = 2.f * W_ru[(fp*5 + 4)*128 + col];
            else             w = W_ru[(fp*5 + m)*128 + col];
            v = (u16)f2bf(w);
        }
        Wt_ru[id] = v;
    }
    int id2 = id - 128*KLIN;
    if (id2 >= 0 && id2 < 64*KLIN){
        int j = id2 & 7;
        int cell = id2 >> 3;
        int col = cell & 63;
        int sq = cell >> 6;
        int kl = sq*8 + j;
        int m = kl / 96, fp = kl - m*96;
        u16 v = 0;
        if (fp < 66){
            float w;
            if (m == 0)      w = W_c[(fp*5 + 0)*64 + col] - W_c[(fp*5 + 2)*64 + col] - W_c[(fp*5 + 4)*64 + col];
            else if (m == 2) w = 2.f * W_c[(fp*5 + 2)*64 + col];
            else if (m == 4) w = 2.f * W_c[(fp*5 + 4)*64 + col];
            else             w = W_c[(fp*5 + m)*64 + col];
            v = (u16)f2bf(w);
        }
        Wt_c[id2] = v;
    }
}

// ---------------- build x0, fp-major chunks: chunk(s,b) at s*32+b holds fp s*8..s*8+7 ----------------
__global__ __launch_bounds__(256) void build_x0_k(const float* __restrict__ inputs,
                                                  const float* __restrict__ hx,
                                                  u16* __restrict__ X0){
    __shared__ float sl[32*72];
    int n = blockIdx.x, t = threadIdx.x;
    #pragma unroll
    for (int i = 0; i < 8; ++i){
        int idx = t + i*256;                // 2048 hx elems
        int b = idx >> 6, f = idx & 63;
        sl[b*72 + 2 + f] = hx[b*HXROW + n*64 + f];
    }
    if (t < 64){
        int b = t >> 1, d = t & 1;
        sl[b*72 + d] = inputs[b*INROW + n*2 + d];
    }
    if (t < 192){
        int b = t / 6, k = t - b*6;
        sl[b*72 + 66 + k] = 0.f;
    }
    __syncthreads();
    #pragma unroll
    for (int i = 0; i < 2; ++i){
        int j = t + i*256;
        if (j < ROWCH){
            int b = j & 31, s = j >> 5;
            const float* p = &sl[b*72 + s*8];
            uint4 o;
            o.x = f2bf(p[0]) | (f2bf(p[1]) << 16);
            o.y = f2bf(p[2]) | (f2bf(p[3]) << 16);
            o.z = f2bf(p[4]) | (f2bf(p[5]) << 16);
            o.w = f2bf(p[6]) | (f2bf(p[7]) << 16);
            ((uint4*)X0)[n*ROWCH + j] = o;
        }
    }
}

__device__ __forceinline__ void acc8(float* a, uint4 q, float v){
    a[0] += v*lo16(q.x); a[1] += v*hi16(q.x);
    a[2] += v*lo16(q.y); a[3] += v*hi16(q.y);
    a[4] += v*lo16(q.z); a[5] += v*hi16(q.z);
    a[6] += v*lo16(q.w); a[7] += v*hi16(q.w);
}
__device__ __forceinline__ uint4 pack8(const float* a){
    uint4 o;
    o.x = f2bf(a[0]) | (f2bf(a[1]) << 16);
    o.y = f2bf(a[2]) | (f2bf(a[3]) << 16);
    o.z = f2bf(a[4]) | (f2bf(a[5]) << 16);
    o.w = f2bf(a[6]) | (f2bf(a[7]) << 16);
    return o;
}

// ---------------- diffusion level 1: X1a = S0*X0, X1b = S1*X0 (one block per node) ----------------
__global__ __launch_bounds__(288) void diff1_k(const u16* __restrict__ X0,
                                               u16* __restrict__ X1a, u16* __restrict__ X1b,
                                               const int* __restrict__ rp,
                                               const int* __restrict__ c0, const float* __restrict__ v0,
                                               const int* __restrict__ c1, const float* __restrict__ v1){
    int t = threadIdx.x;
    if (t >= ROWCH) return;
    int n = blockIdx.x;
    const uint4* xb = (const uint4*)X0;
    float a[8] = {0,0,0,0,0,0,0,0};
    float d[8] = {0,0,0,0,0,0,0,0};
    // support 1: exactly 8 edges
    {
        uint4 q[8]; float vv[8];
        #pragma unroll
        for (int i = 0; i < 8; ++i){
            int c = c1[n*8 + i]; vv[i] = v1[n*8 + i];
            q[i] = xb[(size_t)c*ROWCH + t];
        }
        #pragma unroll
        for (int i = 0; i < 8; ++i) acc8(d, q[i], vv[i]);
    }
    // support 0: CSR, variable degree
    int e = rp[n], end = rp[n+1];
    for (; e + 8 <= end; e += 8){
        uint4 q[8]; float vv[8];
        #pragma unroll
        for (int i = 0; i < 8; ++i){
            int c = c0[e+i]; vv[i] = v0[e+i];
            q[i] = xb[(size_t)c*ROWCH + t];
        }
        #pragma unroll
        for (int i = 0; i < 8; ++i) acc8(a, q[i], vv[i]);
    }
    for (; e < end; ++e){
        int c = c0[e]; float v = v0[e];
        acc8(a, xb[(size_t)c*ROWCH + t], v);
    }
    ((uint4*)X1a)[(size_t)n*ROWCH + t] = pack8(a);
    ((uint4*)X1b)[(size_t)n*ROWCH + t] = pack8(d);
}

// ---------------- diffusion level 2 (Chebyshev folded into W): Y2a = S0*X1a, Y2b = S1*X1b ----------------
__global__ __launch_bounds__(288) void diff2_k(const u16* __restrict__ X1a, const u16* __restrict__ X1b,
                                               u16* __restrict__ Y2a, u16* __restrict__ Y2b,
                                               const int* __restrict__ rp,
                                               const int* __restrict__ c0, const float* __restrict__ v0,
                                               const int* __restrict__ c1, const float* __restrict__ v1){
    int t = threadIdx.x;
    if (t >= ROWCH) return;
    int n = blockIdx.x;
    const uint4* xa = (const uint4*)X1a;
    const uint4* xbb = (const uint4*)X1b;
    float a[8] = {0,0,0,0,0,0,0,0};
    float d[8] = {0,0,0,0,0,0,0,0};
    {
        uint4 q[8]; float vv[8];
        #pragma unroll
        for (int i = 0; i < 8; ++i){
            int c = c1[n*8 + i]; vv[i] = v1[n*8 + i];
            q[i] = xbb[(size_t)c*ROWCH + t];
        }
        #pragma unroll
        for (int i = 0; i < 8; ++i) acc8(d, q[i], vv[i]);
    }
    int e = rp[n], end = rp[n+1];
    for (; e + 8 <= end; e += 8){
        uint4 q[8]; float vv[8];
        #pragma unroll
        for (int i = 0; i < 8; ++i){
            int c = c0[e+i]; vv[i] = v0[e+i];
            q[i] = xa[(size_t)c*ROWCH + t];
        }
        #pragma unroll
        for (int i = 0; i < 8; ++i) acc8(a, q[i], vv[i]);
    }
    for (; e < end; ++e){
        int c = c0[e]; float v = v0[e];
        acc8(a, xa[(size_t)c*ROWCH + t], v);
    }
    ((uint4*)Y2a)[(size_t)n*ROWCH + t] = pack8(a);
    ((uint4*)Y2b)[(size_t)n*ROWCH + t] = pack8(d);
}

// ---------------- GEMM1: sigmoid(Xc@W_ru + b_ru); U out; X0.state <- r*hx (bf16 RMW) ----------------
// 8 waves = 8 nodes (512 thr): halves per-node W-staging traffic vs 4-node blocks.
// B staged in LDS (double-buffered, global_load_lds); LDS tile [q][col][8] conflict-free.
__global__ __launch_bounds__(512) void gemm_ru_k(
        const u16* X0, const u16* __restrict__ X1a, const u16* __restrict__ X2a,
        const u16* __restrict__ X1b, const u16* __restrict__ X2b,
        const u16* __restrict__ WtS,       // [(st*4+q)*128+col][8]
        const float* __restrict__ b_ru,
        u16* __restrict__ U, u16* X0st){
    __shared__ u16 Bs[2][4096];            // 2 x 8KB
    const int t = threadIdx.x;
    const int lane = t & 63, w = t >> 6;
    const int node = blockIdx.x*8 + w;
    const int cIn = lane & 15, q = lane >> 4;
    const size_t noff = (size_t)node * ROWU16;

    const u16* xp[5] = { X0 + noff, X1a + noff, X2a + noff, X1b + noff, X2b + noff };

    f32x4 acc[2][8];
    const f32x4 z4 = {0.f,0.f,0.f,0.f};
    #pragma unroll
    for (int rt = 0; rt < 2; ++rt)
        #pragma unroll
        for (int ct = 0; ct < 8; ++ct) acc[rt][ct] = z4;

    // prologue: stage B tile 0 (512 thr x 16B = 8KB), load A tile 0
    GLDS(WtS + t*8, &Bs[0][w*512]);
    bf16x8 A0 = *(const bf16x8*)&xp[0][(size_t)(q*32 + cIn)*8];
    bf16x8 A1 = *(const bf16x8*)&xp[0][(size_t)(q*32 + 16 + cIn)*8];
    __syncthreads();

    int cur = 0;
    #pragma unroll
    for (int st = 0; st < NSTEPS; ++st){
        bf16x8 p0, p1;
        if (st + 1 < NSTEPS){
            GLDS(WtS + (size_t)(st+1)*4096 + t*8, &Bs[cur^1][w*512]);
            const int m2 = (st+1)/3, s2 = (st+1) - m2*3;
            p0 = *(const bf16x8*)&xp[m2][(size_t)((s2*4 + q)*32 + cIn)*8];
            p1 = *(const bf16x8*)&xp[m2][(size_t)((s2*4 + q)*32 + 16 + cIn)*8];
        }
        bf16x8 cb[8];
        #pragma unroll
        for (int ct = 0; ct < 8; ++ct)
            cb[ct] = *(const bf16x8*)&Bs[cur][(q*128 + ct*16 + cIn)*8];
        #pragma unroll
        for (int ct = 0; ct < 8; ++ct){
            acc[0][ct] = __builtin_amdgcn_mfma_f32_16x16x32_bf16(A0, cb[ct], acc[0][ct], 0,0,0);
            acc[1][ct] = __builtin_amdgcn_mfma_f32_16x16x32_bf16(A1, cb[ct], acc[1][ct], 0,0,0);
        }
        __syncthreads();                    // drains vmcnt for staged tile + A prefetch
        if (st + 1 < NSTEPS){ A0 = p0; A1 = p1; }
        cur ^= 1;
    }

    // epilogue: D row=b (q*4+i within 16-tile, +16*rt), col = ct*16+cIn
    #pragma unroll
    for (int ct = 0; ct < 8; ++ct){
        int col = ct*16 + cIn;
        float bias = b_ru[col];
        #pragma unroll
        for (int rt = 0; rt < 2; ++rt){
            int b0 = rt*16 + q*4;
            f32x4 d = acc[rt][ct];
            if (ct < 4){
                int fp = 2 + col;
                int s = fp >> 3, off = fp & 7;
                #pragma unroll
                for (int i = 0; i < 4; ++i){
                    size_t idx = noff + (size_t)(s*32 + b0 + i)*8 + off;
                    float h = bfu(X0st[idx]);
                    float rg = sigm(d[i] + bias);
                    X0st[idx] = (u16)f2bf(rg * h);
                }
            } else {
                uint2 pk;
                float v0 = sigm(d[0] + bias), v1 = sigm(d[1] + bias);
                float v2 = sigm(d[2] + bias), v3 = sigm(d[3] + bias);
                pk.x = f2bf(v0) | (f2bf(v1) << 16);
                pk.y = f2bf(v2) | (f2bf(v3) << 16);
                *(uint2*)&U[(size_t)node*2048 + (col - 64)*32 + b0] = pk;
            }
        }
    }
}

// ---------------- GEMM2: c = tanh(Xc@W_c + b_c); out = u*hx + (1-u)*c ----------------
__global__ __launch_bounds__(512) void gemm_c_k(
        const u16* __restrict__ X0, const u16* __restrict__ X1a, const u16* __restrict__ X2a,
        const u16* __restrict__ X1b, const u16* __restrict__ X2b,
        const u16* __restrict__ WtS,       // [(st*4+q)*64+col][8]
        const float* __restrict__ b_c, const float* __restrict__ hx,
        const u16* __restrict__ U, float* __restrict__ out){
    __shared__ u16 Bs[2][2048];            // 2 x 4KB
    const int t = threadIdx.x;
    const int lane = t & 63, w = t >> 6;
    const int node = blockIdx.x*8 + w;
    const int cIn = lane & 15, q = lane >> 4;
    const size_t noff = (size_t)node * ROWU16;

    const u16* xp[5] = { X0 + noff, X1a + noff, X2a + noff, X1b + noff, X2b + noff };

    f32x4 acc[2][4];
    const f32x4 z4 = {0.f,0.f,0.f,0.f};
    #pragma unroll
    for (int rt = 0; rt < 2; ++rt)
        #pragma unroll
        for (int ct = 0; ct < 4; ++ct) acc[rt][ct] = z4;

    if (t < 256) GLDS(WtS + t*8, &Bs[0][w*512]);   // 256 thr x 16B = 4KB
    bf16x8 A0 = *(const bf16x8*)&xp[0][(size_t)(q*32 + cIn)*8];
    bf16x8 A1 = *(const bf16x8*)&xp[0][(size_t)(q*32 + 16 + cIn)*8];
    __syncthreads();

    int cur = 0;
    #pragma unroll
    for (int st = 0; st < NSTEPS; ++st){
        bf16x8 p0, p1;
        if (st + 1 < NSTEPS){
            if (t < 256) GLDS(WtS + (size_t)(st+1)*2048 + t*8, &Bs[cur^1][w*512]);
            const int m2 = (st+1)/3, s2 = (st+1) - m2*3;
            p0 = *(const bf16x8*)&xp[m2][(size_t)((s2*4 + q)*32 + cIn)*8];
            p1 = *(const bf16x8*)&xp[m2][(size_t)((s2*4 + q)*32 + 16 + cIn)*8];
        }
        bf16x8 cb[4];
        #pragma unroll
        for (int ct = 0; ct < 4; ++ct)
            cb[ct] = *(const bf16x8*)&Bs[cur][(q*64 + ct*16 + cIn)*8];
        #pragma unroll
        for (int ct = 0; ct < 4; ++ct){
            acc[0][ct] = __builtin_amdgcn_mfma_f32_16x16x32_bf16(A0, cb[ct], acc[0][ct], 0,0,0);
            acc[1][ct] = __builtin_amdgcn_mfma_f32_16x16x32_bf16(A1, cb[ct], acc[1][ct], 0,0,0);
        }
        __syncthreads();
        if (st + 1 < NSTEPS){ A0 = p0; A1 = p1; }
        cur ^= 1;
    }

    #pragma unroll
    for (int ct = 0; ct < 4; ++ct){
        int col = ct*16 + cIn;
        float bias = b_c[col];
        #pragma unroll
        for (int rt = 0; rt < 2; ++rt){
            int b0 = rt*16 + q*4;
            f32x4 d = acc[rt][ct];
            uint2 up = *(const uint2*)&U[(size_t)node*2048 + col*32 + b0];
            float uu[4] = { lo16(up.x), hi16(up.x), lo16(up.y), hi16(up.y) };
            #pragma unroll
            for (int i = 0; i < 4; ++i){
                float c = tanhf(d[i] + bias);
                size_t gi = (size_t)(b0 + i)*HXROW + node*64 + col;
                float h = hx[gi];
                out[gi] = uu[i]*h + (1.f - uu[i])*c;
            }
        }
    }
}

// ---------------- launch ----------------
extern "C" void kernel_launch(void* const* d_in, const int* in_sizes, int n_in,
                              void* d_out, int out_size, void* d_ws, size_t ws_size,
                              hipStream_t stream){
    const float* inputs = (const float*)d_in[0];
    const float* hx     = (const float*)d_in[1];
    const float* W_ru   = (const float*)d_in[2];
    const float* b_ru   = (const float*)d_in[3];
    const float* W_c    = (const float*)d_in[4];
    const float* b_c    = (const float*)d_in[5];
    const int*   s0r    = (const int*)d_in[6];
    const int*   s0c    = (const int*)d_in[7];
    const float* s0v    = (const float*)d_in[8];
    const int*   s1c    = (const int*)d_in[10];
    const float* s1v    = (const float*)d_in[11];
    float* out = (float*)d_out;

    char* ws = (char*)d_ws;
    size_t off = 0;
    auto alloc = [&](size_t bytes) -> char* {
        char* p = ws + off;
        off += (bytes + 255) & ~(size_t)255;
        return p;
    };
    const size_t XBYTES = (size_t)NROW*2 + 2048;   // +guard for k-tail overread of last node
    u16* X0   = (u16*)alloc(XBYTES);
    u16* X1a  = (u16*)alloc(XBYTES);
    u16* X2a  = (u16*)alloc(XBYTES);
    u16* X1b  = (u16*)alloc(XBYTES);
    u16* X2b  = (u16*)alloc(XBYTES);
    u16* U    = (u16*)alloc((size_t)NNODES*2048*2);
    u16* WtRU = (u16*)alloc((size_t)128*KLIN*2);   // 15 steps * 4096 u16
    u16* WtC  = (u16*)alloc((size_t)64*KLIN*2);    // 15 steps * 2048 u16
    int* counts  = (int*)alloc((size_t)NNODES*4);
    int* row_ptr = (int*)alloc((size_t)(NNODES+1)*4);
    int* cursor  = (int*)alloc((size_t)NNODES*4);
    int*   cols_s = (int*)alloc((size_t)EDG*4);
    float* vals_s = (float*)alloc((size_t)EDG*4);
    (void)ws_size; (void)in_sizes; (void)n_in; (void)out_size;

    // CSR build for support 0
    hipMemsetAsync(counts, 0, (size_t)NNODES*4, stream);
    hist_k<<<250, 256, 0, stream>>>(s0r, counts);
    scan_k<<<1, 256, 0, stream>>>(counts, row_ptr, cursor);
    scatter_k<<<250, 256, 0, stream>>>(s0r, s0c, s0v, cursor, cols_s, vals_s);

    prep_w_k<<<360, 256, 0, stream>>>(W_ru, W_c, WtRU, WtC);
    build_x0_k<<<NNODES, 256, 0, stream>>>(inputs, hx, X0);

    // gconv 1 diffusion (Y2 = S*X1, Chebyshev 2x-x0 folded into W)
    diff1_k<<<NNODES, 288, 0, stream>>>(X0, X1a, X1b, row_ptr, cols_s, vals_s, s1c, s1v);
    diff2_k<<<NNODES, 288, 0, stream>>>(X1a, X1b, X2a, X2b, row_ptr, cols_s, vals_s, s1c, s1v);

    // GEMM1 + sigmoid; writes U and X0.state = r*hx
    gemm_ru_k<<<NNODES/8, 512, 0, stream>>>(X0, X1a, X2a, X1b, X2b, WtRU, b_ru, U, X0);

    // gconv 2 diffusion (X0 now holds [inputs, r*hx])
    diff1_k<<<NNODES, 288, 0, stream>>>(X0, X1a, X1b, row_ptr, cols_s, vals_s, s1c, s1v);
    diff2_k<<<NNODES, 288, 0, stream>>>(X1a, X1b, X2a, X2b, row_ptr, cols_s, vals_s, s1c, s1v);

    // GEMM2 + tanh + final gate
    gemm_c_k<<<NNODES/8, 512, 0, stream>>>(X0, X1a, X2a, X1b, X2b, WtC, b_c, hx, U, out);
}

// Round 7
// 664.809 us; speedup vs baseline: 1.1604x; 1.0010x over previous
//
#include <hip/hip_runtime.h>
#include <stdint.h>

typedef unsigned short u16;
typedef unsigned int   u32;

typedef __attribute__((ext_vector_type(8))) short bf16x8;
typedef __attribute__((ext_vector_type(4))) float f32x4;

#define NNODES 8000
#define BSZ    32
#define UNITS  64
#define EDG    64000
#define ROWCH  288           /* 16B chunks per matrix block: 9 slices * 32 b */
#define NODECH 1440          /* chunks per node row: 5 matrices * 288 */
#define NODEU16 11520        /* u16 per node row */
#define KLIN   384           /* 12 steps * 32: per-matrix k=72 (9 slices), 5*72=360 real+pad, 24 tail */
#define NSTEPS 12
#define HXROW  512000
#define INROW  16000

__device__ __forceinline__ u32 f2bf(float f){
    u32 u = __float_as_uint(f);
    return (u + 0x7FFFu + ((u >> 16) & 1u)) >> 16;   // RNE
}
__device__ __forceinline__ float bfu(u16 s){ return __uint_as_float(((u32)s) << 16); }
__device__ __forceinline__ float lo16(u32 u){ return __uint_as_float(u << 16); }
__device__ __forceinline__ float hi16(u32 u){ return __uint_as_float(u & 0xFFFF0000u); }
__device__ __forceinline__ float sigm(float x){ return 1.f / (1.f + __expf(-x)); }

#define GLDS(gsrc, ldst) \
    __builtin_amdgcn_global_load_lds((const __attribute__((address_space(1))) void*)(gsrc), \
                                     (__attribute__((address_space(3))) void*)(ldst), 16, 0, 0)

// ---------------- CSR build for support 0 ----------------
__global__ void hist_k(const int* __restrict__ rows, int* __restrict__ counts){
    int e = blockIdx.x * 256 + threadIdx.x;
    if (e < EDG) atomicAdd(&counts[rows[e]], 1);
}

__global__ __launch_bounds__(256) void scan_k(const int* __restrict__ counts,
                                              int* __restrict__ row_ptr,
                                              int* __restrict__ cursor){
    __shared__ int part[256];
    int t = threadIdx.x;
    int s = 0;
    for (int i = 0; i < 32; ++i){ int r = t*32 + i; if (r < NNODES) s += counts[r]; }
    part[t] = s;
    __syncthreads();
    if (t == 0){
        int run = 0;
        for (int i = 0; i < 256; ++i){ int v = part[i]; part[i] = run; run += v; }
    }
    __syncthreads();
    int run = part[t];
    for (int i = 0; i < 32; ++i){
        int r = t*32 + i;
        if (r < NNODES){ row_ptr[r] = run; cursor[r] = run; run += counts[r]; }
    }
    if (t == 255) row_ptr[NNODES] = run;
}

__global__ void scatter_k(const int* __restrict__ rows, const int* __restrict__ cols,
                          const float* __restrict__ vals, int* __restrict__ cursor,
                          int* __restrict__ cs, float* __restrict__ vs){
    int e = blockIdx.x * 256 + threadIdx.x;
    if (e < EDG){
        int r = rows[e];
        int slot = atomicAdd(&cursor[r], 1);
        cs[slot] = cols[e];
        vs[slot] = vals[e];
    }
}

// ---------------- W pre-permute into per-step staged layout, Chebyshev folded ----------------
// xs stored = [x0, S0x0, S0^2x0, S1x0, S1^2x0]; fold: W0'=W0-W2-W4, W2'=2W2, W4'=2W4.
// kl = st*32 + q*8 + j ; m = kl/72, fp = kl%72 (<66 real). KLIN=384 (kl>=360 -> 0).
// WtS[((st*4+q)*C + col)*8 + j], C = 128 (RU) / 64 (C).
__global__ void prep_w_k(const float* __restrict__ W_ru, const float* __restrict__ W_c,
                         u16* __restrict__ Wt_ru, u16* __restrict__ Wt_c){
    int id = blockIdx.x * 256 + threadIdx.x;
    if (id < 128*KLIN){
        int j = id & 7;
        int cell = id >> 3;
        int col = cell & 127;
        int sq = cell >> 7;                  // st*4+q
        int kl = sq*8 + j;
        int m = kl / 72, fp = kl - m*72;
        u16 v = 0;
        if (m < 5 && fp < 66){
            float w;
            if (m == 0)      w = W_ru[(fp*5 + 0)*128 + col] - W_ru[(fp*5 + 2)*128 + col] - W_ru[(fp*5 + 4)*128 + col];
            else if (m == 2) w = 2.f * W_ru[(fp*5 + 2)*128 + col];
            else if (m == 4) w = 2.f * W_ru[(fp*5 + 4)*128 + col];
            else             w = W_ru[(fp*5 + m)*128 + col];
            v = (u16)f2bf(w);
        }
        Wt_ru[id] = v;
    }
    int id2 = id - 128*KLIN;
    if (id2 >= 0 && id2 < 64*KLIN){
        int j = id2 & 7;
        int cell = id2 >> 3;
        int col = cell & 63;
        int sq = cell >> 6;
        int kl = sq*8 + j;
        int m = kl / 72, fp = kl - m*72;
        u16 v = 0;
        if (m < 5 && fp < 66){
            float w;
            if (m == 0)      w = W_c[(fp*5 + 0)*64 + col] - W_c[(fp*5 + 2)*64 + col] - W_c[(fp*5 + 4)*64 + col];
            else if (m == 2) w = 2.f * W_c[(fp*5 + 2)*64 + col];
            else if (m == 4) w = 2.f * W_c[(fp*5 + 4)*64 + col];
            else             w = W_c[(fp*5 + m)*64 + col];
            v = (u16)f2bf(w);
        }
        Wt_c[id2] = v;
    }
}

// ---------------- build x0 (matrix 0 of unified row), fp-major chunks ----------------
__global__ __launch_bounds__(256) void build_x0_k(const float* __restrict__ inputs,
                                                  const float* __restrict__ hx,
                                                  u16* __restrict__ Xu){
    __shared__ float sl[32*72];
    int n = blockIdx.x, t = threadIdx.x;
    #pragma unroll
    for (int i = 0; i < 8; ++i){
        int idx = t + i*256;                // 2048 hx elems
        int b = idx >> 6, f = idx & 63;
        sl[b*72 + 2 + f] = hx[b*HXROW + n*64 + f];
    }
    if (t < 64){
        int b = t >> 1, d = t & 1;
        sl[b*72 + d] = inputs[b*INROW + n*2 + d];
    }
    if (t < 192){
        int b = t / 6, k = t - b*6;
        sl[b*72 + 66 + k] = 0.f;
    }
    __syncthreads();
    #pragma unroll
    for (int i = 0; i < 2; ++i){
        int j = t + i*256;
        if (j < ROWCH){
            int b = j & 31, s = j >> 5;
            const float* p = &sl[b*72 + s*8];
            uint4 o;
            o.x = f2bf(p[0]) | (f2bf(p[1]) << 16);
            o.y = f2bf(p[2]) | (f2bf(p[3]) << 16);
            o.z = f2bf(p[4]) | (f2bf(p[5]) << 16);
            o.w = f2bf(p[6]) | (f2bf(p[7]) << 16);
            ((uint4*)Xu)[(size_t)n*NODECH + j] = o;
        }
    }
}

__device__ __forceinline__ void acc8(float* a, uint4 q, float v){
    a[0] += v*lo16(q.x); a[1] += v*hi16(q.x);
    a[2] += v*lo16(q.y); a[3] += v*hi16(q.y);
    a[4] += v*lo16(q.z); a[5] += v*hi16(q.z);
    a[6] += v*lo16(q.w); a[7] += v*hi16(q.w);
}
__device__ __forceinline__ uint4 pack8(const float* a){
    uint4 o;
    o.x = f2bf(a[0]) | (f2bf(a[1]) << 16);
    o.y = f2bf(a[2]) | (f2bf(a[3]) << 16);
    o.z = f2bf(a[4]) | (f2bf(a[5]) << 16);
    o.w = f2bf(a[6]) | (f2bf(a[7]) << 16);
    return o;
}

// ---------------- diffusion level 1: m1 = S0*m0, m3 = S1*m0 (one block per node) ----------------
__global__ __launch_bounds__(288) void diff1_k(u16* __restrict__ Xu,
                                               const int* __restrict__ rp,
                                               const int* __restrict__ c0, const float* __restrict__ v0,
                                               const int* __restrict__ c1, const float* __restrict__ v1){
    int t = threadIdx.x;
    if (t >= ROWCH) return;
    int n = blockIdx.x;
    const uint4* xb = (const uint4*)Xu;          // matrix 0 at offset 0
    float a[8] = {0,0,0,0,0,0,0,0};
    float d[8] = {0,0,0,0,0,0,0,0};
    // support 1: exactly 8 edges
    {
        uint4 q[8]; float vv[8];
        #pragma unroll
        for (int i = 0; i < 8; ++i){
            int c = c1[n*8 + i]; vv[i] = v1[n*8 + i];
            q[i] = xb[(size_t)c*NODECH + t];
        }
        #pragma unroll
        for (int i = 0; i < 8; ++i) acc8(d, q[i], vv[i]);
    }
    // support 0: CSR, variable degree
    int e = rp[n], end = rp[n+1];
    for (; e + 8 <= end; e += 8){
        uint4 q[8]; float vv[8];
        #pragma unroll
        for (int i = 0; i < 8; ++i){
            int c = c0[e+i]; vv[i] = v0[e+i];
            q[i] = xb[(size_t)c*NODECH + t];
        }
        #pragma unroll
        for (int i = 0; i < 8; ++i) acc8(a, q[i], vv[i]);
    }
    for (; e < end; ++e){
        int c = c0[e]; float v = v0[e];
        acc8(a, xb[(size_t)c*NODECH + t], v);
    }
    ((uint4*)Xu)[(size_t)n*NODECH + 1*ROWCH + t] = pack8(a);   // m=1: S0*x0
    ((uint4*)Xu)[(size_t)n*NODECH + 3*ROWCH + t] = pack8(d);   // m=3: S1*x0
}

// ---------------- diffusion level 2 (fold in W): m2 = S0*m1, m4 = S1*m3 ----------------
__global__ __launch_bounds__(288) void diff2_k(u16* __restrict__ Xu,
                                               const int* __restrict__ rp,
                                               const int* __restrict__ c0, const float* __restrict__ v0,
                                               const int* __restrict__ c1, const float* __restrict__ v1){
    int t = threadIdx.x;
    if (t >= ROWCH) return;
    int n = blockIdx.x;
    const uint4* xb = (const uint4*)Xu;
    float a[8] = {0,0,0,0,0,0,0,0};
    float d[8] = {0,0,0,0,0,0,0,0};
    {
        uint4 q[8]; float vv[8];
        #pragma unroll
        for (int i = 0; i < 8; ++i){
            int c = c1[n*8 + i]; vv[i] = v1[n*8 + i];
            q[i] = xb[(size_t)c*NODECH + 3*ROWCH + t];         // gather m=3
        }
        #pragma unroll
        for (int i = 0; i < 8; ++i) acc8(d, q[i], vv[i]);
    }
    int e = rp[n], end = rp[n+1];
    for (; e + 8 <= end; e += 8){
        uint4 q[8]; float vv[8];
        #pragma unroll
        for (int i = 0; i < 8; ++i){
            int c = c0[e+i]; vv[i] = v0[e+i];
            q[i] = xb[(size_t)c*NODECH + 1*ROWCH + t];         // gather m=1
        }
        #pragma unroll
        for (int i = 0; i < 8; ++i) acc8(a, q[i], vv[i]);
    }
    for (; e < end; ++e){
        int c = c0[e]; float v = v0[e];
        acc8(a, xb[(size_t)c*NODECH + 1*ROWCH + t], v);
    }
    ((uint4*)Xu)[(size_t)n*NODECH + 2*ROWCH + t] = pack8(a);   // m=2: S0^2*x0
    ((uint4*)Xu)[(size_t)n*NODECH + 4*ROWCH + t] = pack8(d);   // m=4: S1^2*x0
}

// ---------------- GEMM1: sigmoid(Xc@W_ru + b_ru); U out; X0.state <- r*hx (bf16 RMW) ----------------
// 8 waves = 8 nodes (512 thr). Unified row: A reads walk linearly, 12 steps.
// Tail (kl>=360) reads next node's row * W=0; last node covered by zeroed guard.
__global__ __launch_bounds__(512) void gemm_ru_k(
        const u16* Xu,
        const u16* __restrict__ WtS,       // [(st*4+q)*128+col][8]
        const float* __restrict__ b_ru,
        u16* __restrict__ U, u16* X0st){
    __shared__ u16 Bs[2][4096];            // 2 x 8KB
    const int t = threadIdx.x;
    const int lane = t & 63, w = t >> 6;
    const int node = blockIdx.x*8 + w;
    const int cIn = lane & 15, q = lane >> 4;
    const size_t noff = (size_t)node * NODEU16;
    const u16* Xn = Xu + noff;

    f32x4 acc[2][8];
    const f32x4 z4 = {0.f,0.f,0.f,0.f};
    #pragma unroll
    for (int rt = 0; rt < 2; ++rt)
        #pragma unroll
        for (int ct = 0; ct < 8; ++ct) acc[rt][ct] = z4;

    // prologue: stage B tile 0 (512 thr x 16B = 8KB), load A tile 0
    GLDS(WtS + t*8, &Bs[0][w*512]);
    bf16x8 A0 = *(const bf16x8*)&Xn[(size_t)(q*32 + cIn)*8];
    bf16x8 A1 = *(const bf16x8*)&Xn[(size_t)(q*32 + 16 + cIn)*8];
    __syncthreads();

    int cur = 0;
    #pragma unroll
    for (int st = 0; st < NSTEPS; ++st){
        bf16x8 p0, p1;
        if (st + 1 < NSTEPS){
            GLDS(WtS + (size_t)(st+1)*4096 + t*8, &Bs[cur^1][w*512]);
            p0 = *(const bf16x8*)&Xn[(size_t)(((st+1)*4 + q)*32 + cIn)*8];
            p1 = *(const bf16x8*)&Xn[(size_t)(((st+1)*4 + q)*32 + 16 + cIn)*8];
        }
        bf16x8 cb[8];
        #pragma unroll
        for (int ct = 0; ct < 8; ++ct)
            cb[ct] = *(const bf16x8*)&Bs[cur][(q*128 + ct*16 + cIn)*8];
        #pragma unroll
        for (int ct = 0; ct < 8; ++ct){
            acc[0][ct] = __builtin_amdgcn_mfma_f32_16x16x32_bf16(A0, cb[ct], acc[0][ct], 0,0,0);
            acc[1][ct] = __builtin_amdgcn_mfma_f32_16x16x32_bf16(A1, cb[ct], acc[1][ct], 0,0,0);
        }
        __syncthreads();                    // drains vmcnt for staged tile + A prefetch
        if (st + 1 < NSTEPS){ A0 = p0; A1 = p1; }
        cur ^= 1;
    }

    // epilogue: D row=b (q*4+i within 16-tile, +16*rt), col = ct*16+cIn
    #pragma unroll
    for (int ct = 0; ct < 8; ++ct){
        int col = ct*16 + cIn;
        float bias = b_ru[col];
        #pragma unroll
        for (int rt = 0; rt < 2; ++rt){
            int b0 = rt*16 + q*4;
            f32x4 d = acc[rt][ct];
            if (ct < 4){
                int fp = 2 + col;
                int s = fp >> 3, off = fp & 7;
                #pragma unroll
                for (int i = 0; i < 4; ++i){
                    size_t idx = noff + (size_t)(s*32 + b0 + i)*8 + off;
                    float h = bfu(X0st[idx]);
                    float rg = sigm(d[i] + bias);
                    X0st[idx] = (u16)f2bf(rg * h);
                }
            } else {
                uint2 pk;
                float v0 = sigm(d[0] + bias), v1 = sigm(d[1] + bias);
                float v2 = sigm(d[2] + bias), v3 = sigm(d[3] + bias);
                pk.x = f2bf(v0) | (f2bf(v1) << 16);
                pk.y = f2bf(v2) | (f2bf(v3) << 16);
                *(uint2*)&U[(size_t)node*2048 + (col - 64)*32 + b0] = pk;
            }
        }
    }
}

// ---------------- GEMM2: c = tanh(Xc@W_c + b_c); out = u*hx + (1-u)*c ----------------
__global__ __launch_bounds__(512) void gemm_c_k(
        const u16* __restrict__ Xu,
        const u16* __restrict__ WtS,       // [(st*4+q)*64+col][8]
        const float* __restrict__ b_c, const float* __restrict__ hx,
        const u16* __restrict__ U, float* __restrict__ out){
    __shared__ u16 Bs[2][2048];            // 2 x 4KB
    const int t = threadIdx.x;
    const int lane = t & 63, w = t >> 6;
    const int node = blockIdx.x*8 + w;
    const int cIn = lane & 15, q = lane >> 4;
    const size_t noff = (size_t)node * NODEU16;
    const u16* Xn = Xu + noff;

    f32x4 acc[2][4];
    const f32x4 z4 = {0.f,0.f,0.f,0.f};
    #pragma unroll
    for (int rt = 0; rt < 2; ++rt)
        #pragma unroll
        for (int ct = 0; ct < 4; ++ct) acc[rt][ct] = z4;

    if (t < 256) GLDS(WtS + t*8, &Bs[0][w*512]);   // 256 thr x 16B = 4KB
    bf16x8 A0 = *(const bf16x8*)&Xn[(size_t)(q*32 + cIn)*8];
    bf16x8 A1 = *(const bf16x8*)&Xn[(size_t)(q*32 + 16 + cIn)*8];
    __syncthreads();

    int cur = 0;
    #pragma unroll
    for (int st = 0; st < NSTEPS; ++st){
        bf16x8 p0, p1;
        if (st + 1 < NSTEPS){
            if (t < 256) GLDS(WtS + (size_t)(st+1)*2048 + t*8, &Bs[cur^1][w*512]);
            p0 = *(const bf16x8*)&Xn[(size_t)(((st+1)*4 + q)*32 + cIn)*8];
            p1 = *(const bf16x8*)&Xn[(size_t)(((st+1)*4 + q)*32 + 16 + cIn)*8];
        }
        bf16x8 cb[4];
        #pragma unroll
        for (int ct = 0; ct < 4; ++ct)
            cb[ct] = *(const bf16x8*)&Bs[cur][(q*64 + ct*16 + cIn)*8];
        #pragma unroll
        for (int ct = 0; ct < 4; ++ct){
            acc[0][ct] = __builtin_amdgcn_mfma_f32_16x16x32_bf16(A0, cb[ct], acc[0][ct], 0,0,0);
            acc[1][ct] = __builtin_amdgcn_mfma_f32_16x16x32_bf16(A1, cb[ct], acc[1][ct], 0,0,0);
        }
        __syncthreads();
        if (st + 1 < NSTEPS){ A0 = p0; A1 = p1; }
        cur ^= 1;
    }

    #pragma unroll
    for (int ct = 0; ct < 4; ++ct){
        int col = ct*16 + cIn;
        float bias = b_c[col];
        #pragma unroll
        for (int rt = 0; rt < 2; ++rt){
            int b0 = rt*16 + q*4;
            f32x4 d = acc[rt][ct];
            uint2 up = *(const uint2*)&U[(size_t)node*2048 + col*32 + b0];
            float uu[4] = { lo16(up.x), hi16(up.x), lo16(up.y), hi16(up.y) };
            #pragma unroll
            for (int i = 0; i < 4; ++i){
                float c = tanhf(d[i] + bias);
                size_t gi = (size_t)(b0 + i)*HXROW + node*64 + col;
                float h = hx[gi];
                out[gi] = uu[i]*h + (1.f - uu[i])*c;
            }
        }
    }
}

// ---------------- launch ----------------
extern "C" void kernel_launch(void* const* d_in, const int* in_sizes, int n_in,
                              void* d_out, int out_size, void* d_ws, size_t ws_size,
                              hipStream_t stream){
    const float* inputs = (const float*)d_in[0];
    const float* hx     = (const float*)d_in[1];
    const float* W_ru   = (const float*)d_in[2];
    const float* b_ru   = (const float*)d_in[3];
    const float* W_c    = (const float*)d_in[4];
    const float* b_c    = (const float*)d_in[5];
    const int*   s0r    = (const int*)d_in[6];
    const int*   s0c    = (const int*)d_in[7];
    const float* s0v    = (const float*)d_in[8];
    const int*   s1c    = (const int*)d_in[10];
    const float* s1v    = (const float*)d_in[11];
    float* out = (float*)d_out;

    char* ws = (char*)d_ws;
    size_t off = 0;
    auto alloc = [&](size_t bytes) -> char* {
        char* p = ws + off;
        off += (bytes + 255) & ~(size_t)255;
        return p;
    };
    const size_t XU_BYTES = (size_t)NNODES * NODEU16 * 2;
    u16* Xu   = (u16*)alloc(XU_BYTES + 4096);      // +guard for k-tail overread of last node
    u16* U    = (u16*)alloc((size_t)NNODES*2048*2);
    u16* WtRU = (u16*)alloc((size_t)128*KLIN*2);   // 12 steps * 4096 u16
    u16* WtC  = (u16*)alloc((size_t)64*KLIN*2);    // 12 steps * 2048 u16
    int* counts  = (int*)alloc((size_t)NNODES*4);
    int* row_ptr = (int*)alloc((size_t)(NNODES+1)*4);
    int* cursor  = (int*)alloc((size_t)NNODES*4);
    int*   cols_s = (int*)alloc((size_t)EDG*4);
    float* vals_s = (float*)alloc((size_t)EDG*4);
    (void)ws_size; (void)in_sizes; (void)n_in; (void)out_size;

    // CSR build for support 0 + zero the tail guard
    hipMemsetAsync(counts, 0, (size_t)NNODES*4, stream);
    hipMemsetAsync((char*)Xu + XU_BYTES, 0, 4096, stream);
    hist_k<<<250, 256, 0, stream>>>(s0r, counts);
    scan_k<<<1, 256, 0, stream>>>(counts, row_ptr, cursor);
    scatter_k<<<250, 256, 0, stream>>>(s0r, s0c, s0v, cursor, cols_s, vals_s);

    prep_w_k<<<288, 256, 0, stream>>>(W_ru, W_c, WtRU, WtC);
    build_x0_k<<<NNODES, 256, 0, stream>>>(inputs, hx, Xu);

    // gconv 1 diffusion
    diff1_k<<<NNODES, 288, 0, stream>>>(Xu, row_ptr, cols_s, vals_s, s1c, s1v);
    diff2_k<<<NNODES, 288, 0, stream>>>(Xu, row_ptr, cols_s, vals_s, s1c, s1v);

    // GEMM1 + sigmoid; writes U and X0.state = r*hx
    gemm_ru_k<<<NNODES/8, 512, 0, stream>>>(Xu, WtRU, b_ru, U, Xu);

    // gconv 2 diffusion (matrix 0 now holds [inputs, r*hx])
    diff1_k<<<NNODES, 288, 0, stream>>>(Xu, row_ptr, cols_s, vals_s, s1c, s1v);
    diff2_k<<<NNODES, 288, 0, stream>>>(Xu, row_ptr, cols_s, vals_s, s1c, s1v);

    // GEMM2 + tanh + final gate
    gemm_c_k<<<NNODES/8, 512, 0, stream>>>(Xu, WtC, b_c, hx, U, out);
}